// Round 8
// baseline (11288.270 us; speedup 1.0000x reference)
//
#include <hip/hip_runtime.h>
#include <stdint.h>

#define Bdim 4
#define Tdim 2048
#define Vdim 32000
#define Hdim 512
#define MROWS 8192

typedef unsigned short u16;
typedef uint32_t u32;
typedef unsigned long long u64t;
typedef __bf16 bf16x8 __attribute__((ext_vector_type(8)));
typedef float f32x4 __attribute__((ext_vector_type(4)));

__device__ __forceinline__ u16 f2bf(float f) {
  union { float f; u32 u; } a; a.f = f;
  u32 r = a.u + 0x7FFFu + ((a.u >> 16) & 1u);
  return (u16)(r >> 16);
}
__device__ __forceinline__ float unbf(u64t v, int r) {
  union { u32 u; float f; } x; x.u = ((u32)(v >> (16 * r)) & 0xFFFFu) << 16; return x.f;
}
__device__ __forceinline__ u64t pack4(float a, float b, float c, float d) {
  return (u64t)f2bf(a) | ((u64t)f2bf(b) << 16) | ((u64t)f2bf(c) << 32) | ((u64t)f2bf(d) << 48);
}
__device__ __forceinline__ float fast_tanh(float x) {
  float e = __expf(2.f * x);
  return 1.f - 2.f / (e + 1.f);
}

// ---------------- embedding gather -> bf16 ----------------
__global__ void k_gather(const int* __restrict__ x, const float* __restrict__ embed,
                         u16* __restrict__ E) {
  int idx = blockIdx.x * 256 + threadIdx.x;
  int row = idx >> 7;
  int c4  = (idx & 127) << 2;
  int tok = x[row];
  const float4 v = *(const float4*)(embed + (size_t)tok * Hdim + c4);
  *(ushort4*)(E + (size_t)row * Hdim + c4) =
      make_ushort4(f2bf(v.x), f2bf(v.y), f2bf(v.z), f2bf(v.w));
}

// ---------------- fp32 -> bf16 convert ----------------
__global__ void k_f2b(const float* __restrict__ in, u16* __restrict__ out, int n4) {
  int idx = blockIdx.x * 256 + threadIdx.x;
  if (idx >= n4) return;
  const float4 v = *(const float4*)(in + (size_t)idx * 4);
  *(ushort4*)(out + (size_t)idx * 4) =
      make_ushort4(f2bf(v.x), f2bf(v.y), f2bf(v.z), f2bf(v.w));
}

// ---------------- bf16 MFMA GEMM: C = A @ Bw^T + b1 (+b2) ----------------
// aperm=1: A row m at u16 offset (m&2047)*2048 + (m>>11)*512 ([t][b][n] layout).
// obf=1: write bf16, else fp32.
__device__ __forceinline__ void g2l16(const void* g, void* l) {
  __builtin_amdgcn_global_load_lds(
      (const __attribute__((address_space(1))) u32*)g,
      (__attribute__((address_space(3))) u32*)l, 16, 0, 0);
}

__global__ __launch_bounds__(256, 2) void k_gemm(
    const u16* __restrict__ A, const u16* __restrict__ Bw, void* __restrict__ Cv,
    const float* __restrict__ bias1, const float* __restrict__ bias2,
    int M, int N, int K, int ntN, int aperm, int obf)
{
  __shared__ u16 Al[128 * 64];
  __shared__ u16 Bl[128 * 64];
  const int bid = blockIdx.x;
  const int mt = bid / ntN, nt = bid % ntN;
  const int m0 = mt << 7, n0 = nt << 7;
  const int tid = threadIdx.x;
  const int l = tid & 63, w = tid >> 6;
  const int wy = w >> 1, wx = w & 1;
  const int frow = l & 15, fk = (l >> 4) << 3;

  f32x4 acc[4][4];
  #pragma unroll
  for (int a = 0; a < 4; ++a)
    #pragma unroll
    for (int b = 0; b < 4; ++b) acc[a][b] = f32x4{0.f, 0.f, 0.f, 0.f};

  for (int kb = 0; kb < K; kb += 64) {
    __syncthreads();
    #pragma unroll
    for (int is = 0; is < 4; ++is) {
      const int off = tid * 16 + is * 4096;
      const int lrow = off >> 7, lcolB = off & 127;
      const int mrow = m0 + lrow;
      const size_t arow = aperm
          ? (size_t)(mrow & 2047) * 2048 + (size_t)(mrow >> 11) * 512
          : (size_t)mrow * K;
      g2l16(A  + arow + kb + (lcolB >> 1), (char*)Al + off);
      g2l16(Bw + (size_t)(n0 + lrow) * K + kb + (lcolB >> 1), (char*)Bl + off);
    }
    __syncthreads();
    #pragma unroll
    for (int ks = 0; ks < 2; ++ks) {
      bf16x8 af[4], bfr[4];
      #pragma unroll
      for (int mi = 0; mi < 4; ++mi)
        af[mi] = *(const bf16x8*)&Al[((wy * 64 + mi * 16 + frow) << 6) + ks * 32 + fk];
      #pragma unroll
      for (int ni = 0; ni < 4; ++ni)
        bfr[ni] = *(const bf16x8*)&Bl[((wx * 64 + ni * 16 + frow) << 6) + ks * 32 + fk];
      #pragma unroll
      for (int mi = 0; mi < 4; ++mi)
        #pragma unroll
        for (int ni = 0; ni < 4; ++ni)
          acc[mi][ni] = __builtin_amdgcn_mfma_f32_16x16x32_bf16(af[mi], bfr[ni], acc[mi][ni], 0, 0, 0);
    }
  }
  #pragma unroll
  for (int ni = 0; ni < 4; ++ni) {
    const int col = n0 + wx * 64 + ni * 16 + (l & 15);
    float bv = bias1[col];
    if (bias2) bv += bias2[col];
    #pragma unroll
    for (int mi = 0; mi < 4; ++mi) {
      const int row = m0 + wy * 64 + mi * 16 + ((l >> 4) << 2);
      #pragma unroll
      for (int r = 0; r < 4; ++r) {
        const float v = acc[mi][ni][r] + bv;
        if (obf) ((u16*)Cv)[(size_t)(row + r) * N + col] = f2bf(v);
        else     ((float*)Cv)[(size_t)(row + r) * N + col] = v;
      }
    }
  }
}

// ================= single-layer RNN recurrence, one block ====================
// 1 block x 512 threads (8 waves). Wave wv owns neurons [wv*64, wv*64+64).
// h_t = tanh(Whh . h_{t-1} + X[t])   (X has all input terms + biases folded)
// h ping-pongs in LDS (the recurrence never leaves the CU). Whh: K-blocks
// 0..11 in VGPRs (192/thread), 12..15 in LDS (128 KB). No polling, plain mem.
// X is bf16 [b*T+t][n]; h published to Hg as bf16 [t][b][n] (plain stores).
__global__ __launch_bounds__(512, 2) void k_rec(
    const u16* __restrict__ Wb, const u16* __restrict__ Xb,
    u64t* __restrict__ Hg, float* __restrict__ hfin)
{
  __shared__ __align__(16) char smem[139520];
  u16* wlds = (u16*)smem;
  u16* hdb  = (u16*)(smem + 131072);
  const int tid = threadIdx.x;
  const int l = tid & 63, wv = tid >> 6;
  const int nb = wv * 64;
  const int frow = l & 15, fk = (l >> 4) << 3;
  const int vb = l & 15, vg = l >> 4;
  const bool valid = vb < 4;
  const int hrow = (vb & 3) * 528;
  const int nvb = nb + vg * 4;

  // weights: K-blocks 0..11 in VGPRs, 12..15 in LDS
  bf16x8 wf[4][12];
  #pragma unroll
  for (int tl = 0; tl < 4; ++tl)
    #pragma unroll
    for (int kb = 0; kb < 12; ++kb)
      wf[tl][kb] = *(const bf16x8*)&Wb[(size_t)(nb + tl * 16 + frow) * Hdim + kb * 32 + fk];
  #pragma unroll
  for (int tl = 0; tl < 4; ++tl)
    #pragma unroll
    for (int kbl = 0; kbl < 4; ++kbl) {
      bf16x8 f = *(const bf16x8*)&Wb[(size_t)(nb + tl * 16 + frow) * Hdim + (12 + kbl) * 32 + fk];
      *(bf16x8*)&wlds[(((wv * 4 + tl) * 4 + kbl) << 9) + l * 8] = f;
    }
  for (int i = tid; i < 2112; i += 512) ((u32*)hdb)[i] = 0u;   // zero h dbufs
  __syncthreads();

  u64t xc[4], xn[4];
  if (valid) {
    #pragma unroll
    for (int tl = 0; tl < 4; ++tl)
      xc[tl] = *(const u64t*)&Xb[((size_t)vb * Tdim + 0) * Hdim + nvb + tl * 16];
  }

  #pragma unroll 1
  for (int t = 0; t < Tdim; ++t) {
    const u16* hb = hdb + (t & 1) * 2112;
    u16* hw = hdb + (((t & 1)) ^ 1) * 2112;

    // prefetch X[t+1] (hidden under the MFMA block)
    if (valid && t + 1 < Tdim) {
      #pragma unroll
      for (int tl = 0; tl < 4; ++tl)
        xn[tl] = *(const u64t*)&Xb[((size_t)vb * Tdim + t + 1) * Hdim + nvb + tl * 16];
    }

    f32x4 acc[4];
    #pragma unroll
    for (int q = 0; q < 4; ++q) acc[q] = f32x4{0.f, 0.f, 0.f, 0.f};

    #pragma unroll
    for (int kb = 0; kb < 12; ++kb) {
      const bf16x8 hf = *(const bf16x8*)&hb[hrow + kb * 32 + fk];
      #pragma unroll
      for (int tl = 0; tl < 4; ++tl)
        acc[tl] = __builtin_amdgcn_mfma_f32_16x16x32_bf16(wf[tl][kb], hf, acc[tl], 0, 0, 0);
    }
    #pragma unroll
    for (int kbl = 0; kbl < 4; ++kbl) {
      const bf16x8 hf = *(const bf16x8*)&hb[hrow + (12 + kbl) * 32 + fk];
      #pragma unroll
      for (int tl = 0; tl < 4; ++tl) {
        const bf16x8 wl = *(const bf16x8*)&wlds[(((wv * 4 + tl) * 4 + kbl) << 9) + l * 8];
        acc[tl] = __builtin_amdgcn_mfma_f32_16x16x32_bf16(wl, hf, acc[tl], 0, 0, 0);
      }
    }

    if (valid) {
      #pragma unroll
      for (int tl = 0; tl < 4; ++tl) {
        const float h0 = fast_tanh(acc[tl][0] + unbf(xc[tl], 0));
        const float h1 = fast_tanh(acc[tl][1] + unbf(xc[tl], 1));
        const float h2 = fast_tanh(acc[tl][2] + unbf(xc[tl], 2));
        const float h3 = fast_tanh(acc[tl][3] + unbf(xc[tl], 3));
        const int n = nvb + tl * 16;
        const u64t pk = pack4(h0, h1, h2, h3);
        *(u64t*)&hw[vb * 528 + n] = pk;                          // next step (LDS)
        Hg[((size_t)t * 2048 + vb * 512 + n) >> 2] = pk;         // publish (plain)
        if (t == Tdim - 1) {
          float* hd = hfin + vb * Hdim + n;
          hd[0] = h0; hd[1] = h1; hd[2] = h2; hd[3] = h3;
        }
      }
      #pragma unroll
      for (int tl = 0; tl < 4; ++tl) xc[tl] = xn[tl];
    }
    asm volatile("s_waitcnt lgkmcnt(0)" ::: "memory");
    __builtin_amdgcn_sched_barrier(0);
    __builtin_amdgcn_s_barrier();
  }
}

// ---------------- launch ----------------
extern "C" void kernel_launch(void* const* d_in, const int* in_sizes, int n_in,
                              void* d_out, int out_size, void* d_ws, size_t ws_size,
                              hipStream_t stream)
{
  const int*   x     = (const int*)d_in[0];
  const float* embed = (const float*)d_in[1];
  const float* W_ih  = (const float*)d_in[2];
  const float* b_ih  = (const float*)d_in[3];
  const float* W_hh  = (const float*)d_in[4];
  const float* b_hh  = (const float*)d_in[5];
  const float* W_out = (const float*)d_in[6];
  const float* b_out = (const float*)d_in[7];
  float* out = (float*)d_out;

  // workspace layout (~85 MB)
  char* ws = (char*)d_ws;
  u16* E     = (u16*)ws;                                  // 8192*512
  u16* Wihb  = E + (size_t)MROWS * Hdim;                  // 2*512*512
  u16* Whhb  = Wihb + 2 * Hdim * Hdim;                    // 2*512*512
  u16* Woutb = Whhb + 2 * Hdim * Hdim;                    // 32000*512
  u16* X0b   = Woutb + (size_t)Vdim * Hdim;               // 8192*512 bf16 [b*T+t][n]
  u16* X1b   = X0b + (size_t)MROWS * Hdim;                // 8192*512 bf16 [b*T+t][n]
  u64t* H0g  = (u64t*)(X1b + (size_t)MROWS * Hdim);       // [t][b][n] bf16, 8MB
  u64t* H1g  = H0g + (size_t)Tdim * 512;

  k_gather<<<MROWS * (Hdim / 4) / 256, 256, 0, stream>>>(x, embed, E);
  k_f2b<<<(2 * Hdim * Hdim / 4) / 256, 256, 0, stream>>>(W_ih, Wihb, 2 * Hdim * Hdim / 4);
  k_f2b<<<(2 * Hdim * Hdim / 4) / 256, 256, 0, stream>>>(W_hh, Whhb, 2 * Hdim * Hdim / 4);
  k_f2b<<<((size_t)Vdim * Hdim / 4) / 256, 256, 0, stream>>>(W_out, Woutb, Vdim * Hdim / 4);

  // X0 = E @ Wih0^T + b_ih0 + b_hh0 -> bf16 row-major [b*T+t][n]
  k_gemm<<<(MROWS / 128) * (Hdim / 128), 256, 0, stream>>>(
      E, Wihb, (void*)X0b, b_ih, b_hh, MROWS, Hdim, Hdim, Hdim / 128, 0, 1);

  float* hfin = out + (size_t)MROWS * Vdim;

  // layer 0 recurrence (isolated dispatch)
  k_rec<<<1, 512, 0, stream>>>(Whhb, X0b, H0g, hfin);

  // X1 = H0 @ Wih1^T + b_ih1 + b_hh1 -> bf16 [b*T+t][n]  (A in [t][b][n])
  k_gemm<<<(MROWS / 128) * (Hdim / 128), 256, 0, stream>>>(
      (const u16*)H0g, Wihb + Hdim * Hdim, (void*)X1b,
      b_ih + Hdim, b_hh + Hdim, MROWS, Hdim, Hdim, Hdim / 128, 1, 1);

  // layer 1 recurrence (isolated dispatch)
  k_rec<<<1, 512, 0, stream>>>(Whhb + Hdim * Hdim, X1b, H1g, hfin + Bdim * Hdim);

  // out = H1 @ Wout^T + b_out   (A in [t][b][n] layout -> aperm=1, fp32 out)
  k_gemm<<<(MROWS / 128) * (Vdim / 128), 256, 0, stream>>>(
      (const u16*)H1g, Woutb, out, b_out, nullptr, MROWS, Vdim, Hdim, Vdim / 128, 1, 0);
}

// Round 9
// 11252.309 us; speedup vs baseline: 1.0032x; 1.0032x over previous
//
#include <hip/hip_runtime.h>
#include <stdint.h>

#define Bdim 4
#define Tdim 2048
#define Vdim 32000
#define Hdim 512
#define MROWS 8192

typedef unsigned short u16;
typedef uint32_t u32;
typedef unsigned long long u64t;
typedef __bf16 bf16x8 __attribute__((ext_vector_type(8)));
typedef float f32x4 __attribute__((ext_vector_type(4)));

__device__ __forceinline__ u16 f2bf(float f) {
  union { float f; u32 u; } a; a.f = f;
  u32 r = a.u + 0x7FFFu + ((a.u >> 16) & 1u);
  return (u16)(r >> 16);
}
__device__ __forceinline__ float unbf(u64t v, int r) {
  union { u32 u; float f; } x; x.u = ((u32)(v >> (16 * r)) & 0xFFFFu) << 16; return x.f;
}
__device__ __forceinline__ u64t pack4(float a, float b, float c, float d) {
  return (u64t)f2bf(a) | ((u64t)f2bf(b) << 16) | ((u64t)f2bf(c) << 32) | ((u64t)f2bf(d) << 48);
}
__device__ __forceinline__ float fast_tanh(float x) {
  float e = __expf(2.f * x);
  return 1.f - 2.f / (e + 1.f);
}

// ---------------- embedding gather -> bf16 ----------------
__global__ void k_gather(const int* __restrict__ x, const float* __restrict__ embed,
                         u16* __restrict__ E) {
  int idx = blockIdx.x * 256 + threadIdx.x;
  int row = idx >> 7;
  int c4  = (idx & 127) << 2;
  int tok = x[row];
  const float4 v = *(const float4*)(embed + (size_t)tok * Hdim + c4);
  *(ushort4*)(E + (size_t)row * Hdim + c4) =
      make_ushort4(f2bf(v.x), f2bf(v.y), f2bf(v.z), f2bf(v.w));
}

// ---------------- fp32 -> bf16 convert ----------------
__global__ void k_f2b(const float* __restrict__ in, u16* __restrict__ out, int n4) {
  int idx = blockIdx.x * 256 + threadIdx.x;
  if (idx >= n4) return;
  const float4 v = *(const float4*)(in + (size_t)idx * 4);
  *(ushort4*)(out + (size_t)idx * 4) =
      make_ushort4(f2bf(v.x), f2bf(v.y), f2bf(v.z), f2bf(v.w));
}

// ---------------- bf16 MFMA GEMM: C = A @ Bw^T + b1 (+b2) ----------------
// aperm=1: A row m at u16 offset (m&2047)*2048 + (m>>11)*512 ([t][b][n] layout).
// obf=1: write bf16, else fp32.
__device__ __forceinline__ void g2l16(const void* g, void* l) {
  __builtin_amdgcn_global_load_lds(
      (const __attribute__((address_space(1))) u32*)g,
      (__attribute__((address_space(3))) u32*)l, 16, 0, 0);
}

__global__ __launch_bounds__(256, 2) void k_gemm(
    const u16* __restrict__ A, const u16* __restrict__ Bw, void* __restrict__ Cv,
    const float* __restrict__ bias1, const float* __restrict__ bias2,
    int M, int N, int K, int ntN, int aperm, int obf)
{
  __shared__ u16 Al[128 * 64];
  __shared__ u16 Bl[128 * 64];
  const int bid = blockIdx.x;
  const int mt = bid / ntN, nt = bid % ntN;
  const int m0 = mt << 7, n0 = nt << 7;
  const int tid = threadIdx.x;
  const int l = tid & 63, w = tid >> 6;
  const int wy = w >> 1, wx = w & 1;
  const int frow = l & 15, fk = (l >> 4) << 3;

  f32x4 acc[4][4];
  #pragma unroll
  for (int a = 0; a < 4; ++a)
    #pragma unroll
    for (int b = 0; b < 4; ++b) acc[a][b] = f32x4{0.f, 0.f, 0.f, 0.f};

  for (int kb = 0; kb < K; kb += 64) {
    __syncthreads();
    #pragma unroll
    for (int is = 0; is < 4; ++is) {
      const int off = tid * 16 + is * 4096;
      const int lrow = off >> 7, lcolB = off & 127;
      const int mrow = m0 + lrow;
      const size_t arow = aperm
          ? (size_t)(mrow & 2047) * 2048 + (size_t)(mrow >> 11) * 512
          : (size_t)mrow * K;
      g2l16(A  + arow + kb + (lcolB >> 1), (char*)Al + off);
      g2l16(Bw + (size_t)(n0 + lrow) * K + kb + (lcolB >> 1), (char*)Bl + off);
    }
    __syncthreads();
    #pragma unroll
    for (int ks = 0; ks < 2; ++ks) {
      bf16x8 af[4], bfr[4];
      #pragma unroll
      for (int mi = 0; mi < 4; ++mi)
        af[mi] = *(const bf16x8*)&Al[((wy * 64 + mi * 16 + frow) << 6) + ks * 32 + fk];
      #pragma unroll
      for (int ni = 0; ni < 4; ++ni)
        bfr[ni] = *(const bf16x8*)&Bl[((wx * 64 + ni * 16 + frow) << 6) + ks * 32 + fk];
      #pragma unroll
      for (int mi = 0; mi < 4; ++mi)
        #pragma unroll
        for (int ni = 0; ni < 4; ++ni)
          acc[mi][ni] = __builtin_amdgcn_mfma_f32_16x16x32_bf16(af[mi], bfr[ni], acc[mi][ni], 0, 0, 0);
    }
  }
  #pragma unroll
  for (int ni = 0; ni < 4; ++ni) {
    const int col = n0 + wx * 64 + ni * 16 + (l & 15);
    float bv = bias1[col];
    if (bias2) bv += bias2[col];
    #pragma unroll
    for (int mi = 0; mi < 4; ++mi) {
      const int row = m0 + wy * 64 + mi * 16 + ((l >> 4) << 2);
      #pragma unroll
      for (int r = 0; r < 4; ++r) {
        const float v = acc[mi][ni][r] + bv;
        if (obf) ((u16*)Cv)[(size_t)(row + r) * N + col] = f2bf(v);
        else     ((float*)Cv)[(size_t)(row + r) * N + col] = v;
      }
    }
  }
}

// ================= single-layer RNN recurrence, one block ====================
// 1 block x 512 threads (8 waves). Wave wv owns neurons [wv*64, wv*64+64).
// h_t = tanh(Whh . h_{t-1} + X[t])   (X has all input terms + biases folded)
// h ping-pongs in LDS. Whh: K-blocks 0..11 in VGPRs (192/thread), 12..15 in
// LDS (128 KB). __launch_bounds__(512, 1): 256-reg cap -> NO weight spill
// (R8's (512,2) capped at 128 regs and spilled the weight array to scratch).
__global__ __launch_bounds__(512, 1) void k_rec(
    const u16* __restrict__ Wb, const u16* __restrict__ Xb,
    u64t* __restrict__ Hg, float* __restrict__ hfin)
{
  __shared__ __align__(16) char smem[139520];
  u16* wlds = (u16*)smem;
  u16* hdb  = (u16*)(smem + 131072);
  const int tid = threadIdx.x;
  const int l = tid & 63, wv = tid >> 6;
  const int nb = wv * 64;
  const int frow = l & 15, fk = (l >> 4) << 3;
  const int vb = l & 15, vg = l >> 4;
  const bool valid = vb < 4;
  const int hrow = (vb & 3) * 528;
  const int nvb = nb + vg * 4;

  // weights: K-blocks 0..11 in VGPRs, 12..15 in LDS
  bf16x8 wf[4][12];
  #pragma unroll
  for (int tl = 0; tl < 4; ++tl)
    #pragma unroll
    for (int kb = 0; kb < 12; ++kb)
      wf[tl][kb] = *(const bf16x8*)&Wb[(size_t)(nb + tl * 16 + frow) * Hdim + kb * 32 + fk];
  #pragma unroll
  for (int tl = 0; tl < 4; ++tl)
    #pragma unroll
    for (int kbl = 0; kbl < 4; ++kbl) {
      bf16x8 f = *(const bf16x8*)&Wb[(size_t)(nb + tl * 16 + frow) * Hdim + (12 + kbl) * 32 + fk];
      *(bf16x8*)&wlds[(((wv * 4 + tl) * 4 + kbl) << 9) + l * 8] = f;
    }
  for (int i = tid; i < 2112; i += 512) ((u32*)hdb)[i] = 0u;   // zero h dbufs
  __syncthreads();

  u64t xc[4], xn[4];
  if (valid) {
    #pragma unroll
    for (int tl = 0; tl < 4; ++tl)
      xc[tl] = *(const u64t*)&Xb[((size_t)vb * Tdim + 0) * Hdim + nvb + tl * 16];
  }

  #pragma unroll 1
  for (int t = 0; t < Tdim; ++t) {
    const u16* hb = hdb + (t & 1) * 2112;
    u16* hw = hdb + (((t & 1)) ^ 1) * 2112;

    // prefetch X[t+1] (hidden under the MFMA block)
    if (valid && t + 1 < Tdim) {
      #pragma unroll
      for (int tl = 0; tl < 4; ++tl)
        xn[tl] = *(const u64t*)&Xb[((size_t)vb * Tdim + t + 1) * Hdim + nvb + tl * 16];
    }

    f32x4 acc[4];
    #pragma unroll
    for (int q = 0; q < 4; ++q) acc[q] = f32x4{0.f, 0.f, 0.f, 0.f};

    #pragma unroll
    for (int kb = 0; kb < 12; ++kb) {
      const bf16x8 hf = *(const bf16x8*)&hb[hrow + kb * 32 + fk];
      #pragma unroll
      for (int tl = 0; tl < 4; ++tl)
        acc[tl] = __builtin_amdgcn_mfma_f32_16x16x32_bf16(wf[tl][kb], hf, acc[tl], 0, 0, 0);
    }
    #pragma unroll
    for (int kbl = 0; kbl < 4; ++kbl) {
      const bf16x8 hf = *(const bf16x8*)&hb[hrow + (12 + kbl) * 32 + fk];
      #pragma unroll
      for (int tl = 0; tl < 4; ++tl) {
        const bf16x8 wl = *(const bf16x8*)&wlds[(((wv * 4 + tl) * 4 + kbl) << 9) + l * 8];
        acc[tl] = __builtin_amdgcn_mfma_f32_16x16x32_bf16(wl, hf, acc[tl], 0, 0, 0);
      }
    }

    if (valid) {
      #pragma unroll
      for (int tl = 0; tl < 4; ++tl) {
        const float h0 = fast_tanh(acc[tl][0] + unbf(xc[tl], 0));
        const float h1 = fast_tanh(acc[tl][1] + unbf(xc[tl], 1));
        const float h2 = fast_tanh(acc[tl][2] + unbf(xc[tl], 2));
        const float h3 = fast_tanh(acc[tl][3] + unbf(xc[tl], 3));
        const int n = nvb + tl * 16;
        const u64t pk = pack4(h0, h1, h2, h3);
        *(u64t*)&hw[vb * 528 + n] = pk;                          // next step (LDS)
        Hg[((size_t)t * 2048 + vb * 512 + n) >> 2] = pk;         // publish (plain)
        if (t == Tdim - 1) {
          float* hd = hfin + vb * Hdim + n;
          hd[0] = h0; hd[1] = h1; hd[2] = h2; hd[3] = h3;
        }
      }
      #pragma unroll
      for (int tl = 0; tl < 4; ++tl) xc[tl] = xn[tl];
    }
    asm volatile("s_waitcnt lgkmcnt(0)" ::: "memory");
    __builtin_amdgcn_sched_barrier(0);
    __builtin_amdgcn_s_barrier();
  }
}

// ---------------- launch ----------------
extern "C" void kernel_launch(void* const* d_in, const int* in_sizes, int n_in,
                              void* d_out, int out_size, void* d_ws, size_t ws_size,
                              hipStream_t stream)
{
  const int*   x     = (const int*)d_in[0];
  const float* embed = (const float*)d_in[1];
  const float* W_ih  = (const float*)d_in[2];
  const float* b_ih  = (const float*)d_in[3];
  const float* W_hh  = (const float*)d_in[4];
  const float* b_hh  = (const float*)d_in[5];
  const float* W_out = (const float*)d_in[6];
  const float* b_out = (const float*)d_in[7];
  float* out = (float*)d_out;

  // workspace layout (~85 MB)
  char* ws = (char*)d_ws;
  u16* E     = (u16*)ws;                                  // 8192*512
  u16* Wihb  = E + (size_t)MROWS * Hdim;                  // 2*512*512
  u16* Whhb  = Wihb + 2 * Hdim * Hdim;                    // 2*512*512
  u16* Woutb = Whhb + 2 * Hdim * Hdim;                    // 32000*512
  u16* X0b   = Woutb + (size_t)Vdim * Hdim;               // 8192*512 bf16 [b*T+t][n]
  u16* X1b   = X0b + (size_t)MROWS * Hdim;                // 8192*512 bf16 [b*T+t][n]
  u64t* H0g  = (u64t*)(X1b + (size_t)MROWS * Hdim);       // [t][b][n] bf16, 8MB
  u64t* H1g  = H0g + (size_t)Tdim * 512;

  k_gather<<<MROWS * (Hdim / 4) / 256, 256, 0, stream>>>(x, embed, E);
  k_f2b<<<(2 * Hdim * Hdim / 4) / 256, 256, 0, stream>>>(W_ih, Wihb, 2 * Hdim * Hdim / 4);
  k_f2b<<<(2 * Hdim * Hdim / 4) / 256, 256, 0, stream>>>(W_hh, Whhb, 2 * Hdim * Hdim / 4);
  k_f2b<<<((size_t)Vdim * Hdim / 4) / 256, 256, 0, stream>>>(W_out, Woutb, Vdim * Hdim / 4);

  // X0 = E @ Wih0^T + b_ih0 + b_hh0 -> bf16 row-major [b*T+t][n]
  k_gemm<<<(MROWS / 128) * (Hdim / 128), 256, 0, stream>>>(
      E, Wihb, (void*)X0b, b_ih, b_hh, MROWS, Hdim, Hdim, Hdim / 128, 0, 1);

  float* hfin = out + (size_t)MROWS * Vdim;

  // layer 0 recurrence (isolated dispatch)
  k_rec<<<1, 512, 0, stream>>>(Whhb, X0b, H0g, hfin);

  // X1 = H0 @ Wih1^T + b_ih1 + b_hh1 -> bf16 [b*T+t][n]  (A in [t][b][n])
  k_gemm<<<(MROWS / 128) * (Hdim / 128), 256, 0, stream>>>(
      (const u16*)H0g, Wihb + Hdim * Hdim, (void*)X1b,
      b_ih + Hdim, b_hh + Hdim, MROWS, Hdim, Hdim, Hdim / 128, 1, 1);

  // layer 1 recurrence (isolated dispatch)
  k_rec<<<1, 512, 0, stream>>>(Whhb + Hdim * Hdim, X1b, H1g, hfin + Bdim * Hdim);

  // out = H1 @ Wout^T + b_out   (A in [t][b][n] layout -> aperm=1, fp32 out)
  k_gemm<<<(MROWS / 128) * (Vdim / 128), 256, 0, stream>>>(
      (const u16*)H1g, Woutb, out, b_out, nullptr, MROWS, Vdim, Hdim, Vdim / 128, 1, 0);
}